// Round 6
// baseline (100.157 us; speedup 1.0000x reference)
//
#include <hip/hip_runtime.h>

typedef __fp16 f16x4 __attribute__((ext_vector_type(4)));
typedef __fp16 f16x2 __attribute__((ext_vector_type(2)));
typedef float f32x4 __attribute__((ext_vector_type(4)));

__device__ __forceinline__ f16x4 cat(f16x2 lo, f16x2 hi) {
    return __builtin_shufflevector(lo, hi, 0, 1, 2, 3);
}
__device__ __forceinline__ f16x2 u2h(unsigned v) {
    union { unsigned u; f16x2 h; } x; x.u = v; return x.h;
}
template <int CTRL>
__device__ __forceinline__ float dpp_add(float v) {
    int s = __builtin_amdgcn_update_dpp(0, __float_as_int(v), CTRL, 0xf, 0xf, true);
    return v + __int_as_float(s);
}

// Two samples per wave with their serial MFMA chains manually interleaved
// (hides MFMA->VALU dependent-chain stalls inside the wave), 4 waves/SIMD
// (128 VGPR budget -> no scratch spills; R5's (256,8) bound forced spills).
// Chain A_{s+1}=x*A_s via mfma_f32_16x16x16f16: C/D layout == B-operand
// layout for this shape, so acc feeds the next B with just a pkrtz pack.
// Trace reduction via 2-MFMA passes -> lane-parallel polynomial epilogue.
__global__ __launch_bounds__(256, 4) void acoef_kernel(
    const float* __restrict__ x,
    const float* __restrict__ coef,
    float* __restrict__ out,
    int B)
{
    const int lane = threadIdx.x & 63;
    const int wid  = (blockIdx.x * 256 + threadIdx.x) >> 6;  // global wave id
    const int nw   = gridDim.x * 4;                          // total waves

    const int n = lane & 15;   // col (C) / n (B) / m (A)
    const int q = lane >> 4;   // quad -> k block
    const bool diagsel = ((n >> 2) == q);

    // loop-invariant epilogue constants
    unsigned slo = (n == 0 ? 0x3C00u : 0u) | (n == 1 ? 0x3C000000u : 0u);
    unsigned shi = (n == 2 ? 0x3C00u : 0u) | (n == 3 ? 0x3C000000u : 0u);
    const f16x4 selB  = cat(u2h(slo), u2h(shi));
    const f16x4 onesA = cat(u2h(0x3C003C00u), u2h(0x3C003C00u));
    const f32x4 zero  = {0.f, 0.f, 0.f, 0.f};
    float4 cf[3]; float scl[3];
    #pragma unroll
    for (int p = 0; p < 3; ++p) {
        int s = 4 * p + n;
        int idx = s > 9 ? 9 : s;
        cf[p]  = *(const float4*)(coef + 4 * idx);
        scl[p] = __int_as_float((127 - 8 * s) << 23);   // 256^{-s}
    }

    const int aoff = n * 16 + 4 * q;   // A: row n, cols 4q..4q+3
    const int boff = 64 * q + n;       // B: col n, rows 4q..4q+3

    const int npair = B >> 1;
    int pp = wid;

    // prologue: load pair (samples 2pp, 2pp+1)
    float4 a[2], bv[2];
    {
        const float* x0 = x + (size_t)(2 * pp) * 256;
        const float* x1 = x0 + 256;
        a[0]  = *(const float4*)(x0 + aoff);
        a[1]  = *(const float4*)(x1 + aoff);
        bv[0] = make_float4(x0[boff], x0[boff + 16], x0[boff + 32], x0[boff + 48]);
        bv[1] = make_float4(x1[boff], x1[boff + 16], x1[boff + 32], x1[boff + 48]);
    }

    while (true) {
        const int pn = pp + nw;
        const bool more = (pn < npair);
        // prefetch next pair (clamped to current on last iteration)
        const float* y0 = x + (size_t)(2 * (more ? pn : pp)) * 256;
        const float* y1 = y0 + 256;
        float4 na0 = *(const float4*)(y0 + aoff);
        float4 na1 = *(const float4*)(y1 + aoff);
        float4 nb0 = make_float4(y0[boff], y0[boff + 16], y0[boff + 32], y0[boff + 48]);
        float4 nb1 = make_float4(y1[boff], y1[boff + 16], y1[boff + 32], y1[boff + 48]);

        // ---- compute both chains, interleaved ----
        f16x4 xA[2], xB[2];
        f32x4 acc[2];
        #pragma unroll
        for (int c = 0; c < 2; ++c) {
            xA[c] = cat(__builtin_amdgcn_cvt_pkrtz(a[c].x, a[c].y),
                        __builtin_amdgcn_cvt_pkrtz(a[c].z, a[c].w));
            xB[c] = cat(__builtin_amdgcn_cvt_pkrtz(bv[c].x, bv[c].y),
                        __builtin_amdgcn_cvt_pkrtz(bv[c].z, bv[c].w));
            acc[c] = __builtin_amdgcn_mfma_f32_16x16x16f16(xA[c], xB[c], zero, 0, 0, 0);
        }

        f16x2 prpk[2][6];
        float trf[2];
        #pragma unroll
        for (int st = 0; st < 10; ++st) {
            #pragma unroll
            for (int c = 0; c < 2; ++c) {
                float sA = (n & 1) ? acc[c][1] : acc[c][0];
                float sB = (n & 1) ? acc[c][3] : acc[c][2];
                float dv = (n & 2) ? sB : sA;
                float tr = diagsel ? dv : 0.0f;
                if (st & 1) prpk[c][st >> 1] = __builtin_amdgcn_cvt_pkrtz(trf[c], tr);
                else        trf[c] = tr;
            }
            if (st < 9) {
                #pragma unroll
                for (int c = 0; c < 2; ++c) {
                    f16x4 bf = cat(__builtin_amdgcn_cvt_pkrtz(acc[c][0], acc[c][1]),
                                   __builtin_amdgcn_cvt_pkrtz(acc[c][2], acc[c][3]));
                    acc[c] = __builtin_amdgcn_mfma_f32_16x16x16f16(xA[c], bf, zero, 0, 0, 0);
                }
            }
        }
        prpk[0][5] = u2h(0u);
        prpk[1][5] = u2h(0u);

        float res[2] = {0.0f, 0.0f};
        #pragma unroll
        for (int p = 0; p < 3; ++p) {
            #pragma unroll
            for (int c = 0; c < 2; ++c) {
                f16x4 Ap = cat(prpk[c][2 * p], prpk[c][2 * p + 1]);
                f32x4 c1 = __builtin_amdgcn_mfma_f32_16x16x16f16(Ap, selB, zero, 0, 0, 0);
                f16x4 Bp = cat(__builtin_amdgcn_cvt_pkrtz(c1[0], c1[1]),
                               __builtin_amdgcn_cvt_pkrtz(c1[2], c1[3]));
                f32x4 c2 = __builtin_amdgcn_mfma_f32_16x16x16f16(onesA, Bp, zero, 0, 0, 0);
                float t = c2[0];                 // t_{4p+n} for n<4, else 0
                float sv = t * 0x1p-8f;          // t / 256
                float h = fmaf(sv, cf[p].w, cf[p].z);
                h = fmaf(sv, h, cf[p].y);
                h = fmaf(sv, h, cf[p].x);
                res[c] = fmaf(sv * h, scl[p], res[c]);
            }
        }
        #pragma unroll
        for (int c = 0; c < 2; ++c) {
            res[c] = dpp_add<0xB1>(res[c]);   // quad_perm [1,0,3,2]
            res[c] = dpp_add<0x4E>(res[c]);   // quad_perm [2,3,0,1]
        }
        if (lane == 0) *(float2*)(out + 2 * pp) = make_float2(res[0], res[1]);

        if (!more) break;
        pp = pn;
        a[0] = na0; a[1] = na1; bv[0] = nb0; bv[1] = nb1;
    }
}

extern "C" void kernel_launch(void* const* d_in, const int* in_sizes, int n_in,
                              void* d_out, int out_size, void* d_ws, size_t ws_size,
                              hipStream_t stream) {
    const float* x    = (const float*)d_in[0];   // [65536, 16, 16] fp32
    const float* coef = (const float*)d_in[1];   // [10, 4] fp32
    float* out        = (float*)d_out;           // [65536] fp32
    const int B = in_sizes[0] / 256;             // 65536 samples
    // 1024 blocks x 4 waves = 4096 waves x 2 chains -> 8 pairs/wave, 4 waves/SIMD
    acoef_kernel<<<dim3(1024), dim3(256), 0, stream>>>(x, coef, out, B);
}

// Round 7
// 97.128 us; speedup vs baseline: 1.0312x; 1.0312x over previous
//
#include <hip/hip_runtime.h>

typedef __fp16 f16x4 __attribute__((ext_vector_type(4)));
typedef __fp16 f16x2 __attribute__((ext_vector_type(2)));
typedef float f32x4 __attribute__((ext_vector_type(4)));

__device__ __forceinline__ f16x4 cat(f16x2 lo, f16x2 hi) {
    return __builtin_shufflevector(lo, hi, 0, 1, 2, 3);
}
__device__ __forceinline__ f16x2 u2h(unsigned v) {
    union { unsigned u; f16x2 h; } x; x.u = v; return x.h;
}
template <int CTRL>
__device__ __forceinline__ float dpp_add(float v) {
    int s = __builtin_amdgcn_update_dpp(0, __float_as_int(v), CTRL, 0xf, 0xf, true);
    return v + __int_as_float(s);
}

// One sample per wave, ONE vmem load per sample:
// the coalesced A-load (lane(n,q) = row n, cols 4q..4q+3) covers all 256
// elements; the B-operand copy of x is derived on-chip via D = x_A * I_B,
// which lands x in C layout == B-operand layout (16x16x16f16 identity).
// This removes the 4 strided scalar loads + 64-bit addressing that kept
// memory latency on the critical path in rounds 4-6.
// Chain A_{s+1}=x*A_s (C==B: repack via pkrtz only); trace reduction via
// 2-MFMA passes -> lane-parallel polynomial epilogue.
__global__ __launch_bounds__(256, 6) void acoef_kernel(
    const float* __restrict__ x,
    const float* __restrict__ coef,
    float* __restrict__ out)
{
    const int lane = threadIdx.x & 63;
    const int b = (blockIdx.x * 256 + (int)threadIdx.x) >> 6;

    const int n = lane & 15;   // col (C) / n (B) / m (A)
    const int q = lane >> 4;   // quad -> k block
    const bool diagsel = ((n >> 2) == q);  // lane holds C[n][n] / I rows

    // ---- the single global load: A[m=n][k=4q..4q+3] ----
    const float4 a = *(const float4*)(x + (size_t)b * 256 + n * 16 + 4 * q);

    // ---- lane-constant fragments ----
    // identity in B layout: B[4q+j][n] = (4q+j==n); nonzero only when diagsel
    unsigned ilo = 0, ihi = 0;
    if (diagsel) {
        ilo = ((n & 3) == 0 ? 0x3C00u : 0u) | ((n & 3) == 1 ? 0x3C000000u : 0u);
        ihi = ((n & 3) == 2 ? 0x3C00u : 0u) | ((n & 3) == 3 ? 0x3C000000u : 0u);
    }
    const f16x4 idB = cat(u2h(ilo), u2h(ihi));
    // trace-reduction selector: B[4q+j][n] = (j==n), and ones for pass 2
    unsigned slo = (n == 0 ? 0x3C00u : 0u) | (n == 1 ? 0x3C000000u : 0u);
    unsigned shi = (n == 2 ? 0x3C00u : 0u) | (n == 3 ? 0x3C000000u : 0u);
    const f16x4 selB  = cat(u2h(slo), u2h(shi));
    const f16x4 onesA = cat(u2h(0x3C003C00u), u2h(0x3C003C00u));
    const f32x4 zero  = {0.f, 0.f, 0.f, 0.f};

    // per-lane coef rows + 256^{-s} scales (s = 4p + n, clamped; t=0 past 9)
    float4 cf[3]; float scl[3];
    #pragma unroll
    for (int p = 0; p < 3; ++p) {
        int s = 4 * p + n;
        int idx = s > 9 ? 9 : s;
        cf[p]  = *(const float4*)(coef + 4 * idx);
        scl[p] = __int_as_float((127 - 8 * s) << 23);
    }

    // ---- build operands: xA from the load, xB = xA * I ----
    f16x4 xA = cat(__builtin_amdgcn_cvt_pkrtz(a.x, a.y),
                   __builtin_amdgcn_cvt_pkrtz(a.z, a.w));
    f32x4 d = __builtin_amdgcn_mfma_f32_16x16x16f16(xA, idB, zero, 0, 0, 0);
    f16x4 xB = cat(__builtin_amdgcn_cvt_pkrtz(d[0], d[1]),
                   __builtin_amdgcn_cvt_pkrtz(d[2], d[3]));

    f32x4 acc = __builtin_amdgcn_mfma_f32_16x16x16f16(xA, xB, zero, 0, 0, 0); // x^2

    // ---- power chain + trace partial extraction ----
    f16x2 prpk[6];
    float trf = 0.0f;
    #pragma unroll
    for (int st = 0; st < 10; ++st) {
        float sA = (n & 1) ? acc[1] : acc[0];
        float sB = (n & 1) ? acc[3] : acc[2];
        float dv = (n & 2) ? sB : sA;
        float tr = diagsel ? dv : 0.0f;
        if (st & 1) prpk[st >> 1] = __builtin_amdgcn_cvt_pkrtz(trf, tr);
        else        trf = tr;

        if (st < 9) {
            f16x4 bf = cat(__builtin_amdgcn_cvt_pkrtz(acc[0], acc[1]),
                           __builtin_amdgcn_cvt_pkrtz(acc[2], acc[3]));
            acc = __builtin_amdgcn_mfma_f32_16x16x16f16(xA, bf, zero, 0, 0, 0);
        }
    }
    prpk[5] = u2h(0u);  // traces 10,11 = 0 pad

    // ---- trace reduction (2 MFMAs per 4 traces) + polynomial ----
    float result = 0.0f;
    #pragma unroll
    for (int p = 0; p < 3; ++p) {
        f16x4 Ap = cat(prpk[2 * p], prpk[2 * p + 1]);
        f32x4 c1 = __builtin_amdgcn_mfma_f32_16x16x16f16(Ap, selB, zero, 0, 0, 0);
        f16x4 Bp = cat(__builtin_amdgcn_cvt_pkrtz(c1[0], c1[1]),
                       __builtin_amdgcn_cvt_pkrtz(c1[2], c1[3]));
        f32x4 c2 = __builtin_amdgcn_mfma_f32_16x16x16f16(onesA, Bp, zero, 0, 0, 0);
        float t = c2[0];             // t_{4p+n} for n<4, else 0
        float sv = t * 0x1p-8f;      // t / 256
        float h = fmaf(sv, cf[p].w, cf[p].z);
        h = fmaf(sv, h, cf[p].y);
        h = fmaf(sv, h, cf[p].x);
        result = fmaf(sv * h, scl[p], result);
    }
    result = dpp_add<0xB1>(result);  // quad_perm [1,0,3,2]
    result = dpp_add<0x4E>(result);  // quad_perm [2,3,0,1]
    if (lane == 0) out[b] = result;
}

extern "C" void kernel_launch(void* const* d_in, const int* in_sizes, int n_in,
                              void* d_out, int out_size, void* d_ws, size_t ws_size,
                              hipStream_t stream) {
    const float* x    = (const float*)d_in[0];   // [65536, 16, 16] fp32
    const float* coef = (const float*)d_in[1];   // [10, 4] fp32
    float* out        = (float*)d_out;           // [65536] fp32
    const int B = in_sizes[0] / 256;             // 65536 samples
    acoef_kernel<<<dim3(B / 4), dim3(256), 0, stream>>>(x, coef, out);
}